// Round 5
// baseline (121.495 us; speedup 1.0000x reference)
//
#include <hip/hip_runtime.h>

#define HH 1024
#define WW 1024

typedef __fp16 h2 __attribute__((ext_vector_type(2)));

// Block tile: 128 cols x 16 rows, halo 2 -> 20 rows x 132 cols.
// Image staged ONCE per block into LDS as pre-packed fp16 pairs in BOTH
// alignments: E2[r][k]=(t[2k],t[2k+1]), O2[r][k]=(t[2k+1],t[2k+2]) where
// t = tile col (t=0 <-> global col bx0-2, edge-clamped like jnp.pad 'edge').
// This replaces R4's 48 clamped scalar global loads + 48 cvt_pkrtz per
// thread with ~16 coalesced loads + ~10 cvt amortized block-wide; the conv
// core (v_dot2_f32_f16, taps paired along dx) is unchanged from R4.
// Even rows (computed pixel at x0+1) use O2 pairs; odd rows use E2 pairs;
// third pair's second filter element is 0 so E2/O2 overrun slots are inert.
__global__ __launch_bounds__(256, 2)
void demosaick_kernel(const float* __restrict__ mosaick,
                      const float* __restrict__ sel_filts,
                      const float* __restrict__ green_filts,
                      float* __restrict__ out) {
    __shared__ h2 E2[20][66];      // 5280 B
    __shared__ h2 O2[20][66];      // 5280 B
    __shared__ h2 filt2[15 * 16];  // 960 B  [dy*3+pair][ch]; sel 0-7, green 8-15

    const int tid = threadIdx.y * 64 + threadIdx.x;
    const int b   = blockIdx.z;
    const int by0 = blockIdx.y * 16;
    const int bx0 = blockIdx.x * 128;
    const float* img = mosaick + (size_t)b * (HH * WW);

    // ---- filter staging (240 threads) ----
    if (tid < 240) {
        int ch = tid & 15;
        int t  = tid >> 4;          // 0..14 = dy*3 + pair
        int dy = t / 3;
        int pr = t - dy * 3;
        int dx0 = 2 * pr;
        const float* src = (ch < 8) ? sel_filts : green_filts;
        int base = (ch & 7) * 25 + dy * 5 + dx0;
        float v0 = src[base];
        float v1 = (dx0 + 1 < 5) ? src[base + 1] : 0.f;
        filt2[tid] = __builtin_amdgcn_cvt_pkrtz(v0, v1);
    }

    // ---- image tile staging: 20 rows x 66 pair-entries ----
    for (int idx = tid; idx < 20 * 66; idx += 256) {
        int r = idx / 66;
        int k = idx - r * 66;
        int gy = by0 - 2 + r;
        gy = gy < 0 ? 0 : (gy > HH - 1 ? HH - 1 : gy);
        const float* rp = img + (size_t)gy * WW;
        int g0 = bx0 - 2 + 2 * k;
        int c0 = g0 < 0 ? 0 : (g0 > WW - 1 ? WW - 1 : g0);
        int c1 = g0 + 1 < 0 ? 0 : (g0 + 1 > WW - 1 ? WW - 1 : g0 + 1);
        int c2 = g0 + 2 < 0 ? 0 : (g0 + 2 > WW - 1 ? WW - 1 : g0 + 2);
        float f0 = rp[c0], f1 = rp[c1], f2 = rp[c2];
        E2[r][k] = __builtin_amdgcn_cvt_pkrtz(f0, f1);
        O2[r][k] = __builtin_amdgcn_cvt_pkrtz(f1, f2);
    }
    __syncthreads();

    const int lx = threadIdx.x;                 // pair-column index in tile
    const int y0 = by0 + threadIdx.y * 4;       // even
    const int x0 = bx0 + lx * 2;                // even

    // ---- window pairs from LDS: rows y0-2..y0+5 -> tile rows ty*4 + j ----
    h2 hE[8][3];    // even-aligned pairs (w0,w1)(w2,w3)(w4,*)  — odd rows
    h2 hO[8][3];    // odd-aligned  pairs (w1,w2)(w3,w4)(w5,*)  — even rows
    #pragma unroll
    for (int j = 0; j < 8; ++j) {
        int r = threadIdx.y * 4 + j;
        #pragma unroll
        for (int pr = 0; pr < 3; ++pr) {
            hE[j][pr] = E2[r][lx + pr];
            hO[j][pr] = O2[r][lx + pr];
        }
    }

    // ---- selection bank (ch 0..7) ----
    float accS[4][8];
    #pragma unroll
    for (int p = 0; p < 4; ++p)
        #pragma unroll
        for (int c = 0; c < 8; ++c) accS[p][c] = 0.f;

    #pragma unroll
    for (int dy = 0; dy < 5; ++dy) {
        #pragma unroll
        for (int pr = 0; pr < 3; ++pr) {
            const h2* fp = &filt2[(dy * 3 + pr) * 16];
            h2 f[8];
            #pragma unroll
            for (int c = 0; c < 8; ++c) f[c] = fp[c];
            #pragma unroll
            for (int p = 0; p < 4; ++p) {
                h2 wp = (p & 1) ? hE[p + dy][pr] : hO[p + dy][pr];
                #pragma unroll
                for (int c = 0; c < 8; ++c)
                    accS[p][c] = __builtin_amdgcn_fdot2(wp, f[c], accS[p][c], false);
            }
        }
    }

    // ---- softmax weights (overwrite accS with exp terms) ----
    const float L2E = 1.44269504f;
    float sum[4], gh[4];
    #pragma unroll
    for (int p = 0; p < 4; ++p) {
        float m = accS[p][0];
        #pragma unroll
        for (int c = 1; c < 8; ++c) m = fmaxf(m, accS[p][c]);
        float mL = m * L2E;
        float s = 0.f;
        #pragma unroll
        for (int c = 0; c < 8; ++c) {
            float e = __builtin_amdgcn_exp2f(fmaf(accS[p][c], L2E, -mL));
            accS[p][c] = e;
            s += e;
        }
        sum[p] = s;
        gh[p] = 0.f;
    }

    // ---- green bank (ch 8..15) in two 4-channel halves (VGPR control) ----
    #pragma unroll
    for (int hlf = 0; hlf < 2; ++hlf) {
        float accG[4][4];
        #pragma unroll
        for (int p = 0; p < 4; ++p)
            #pragma unroll
            for (int c = 0; c < 4; ++c) accG[p][c] = 0.f;

        #pragma unroll
        for (int dy = 0; dy < 5; ++dy) {
            #pragma unroll
            for (int pr = 0; pr < 3; ++pr) {
                const h2* fp = &filt2[(dy * 3 + pr) * 16 + 8 + 4 * hlf];
                h2 f[4];
                #pragma unroll
                for (int c = 0; c < 4; ++c) f[c] = fp[c];
                #pragma unroll
                for (int p = 0; p < 4; ++p) {
                    h2 wp = (p & 1) ? hE[p + dy][pr] : hO[p + dy][pr];
                    #pragma unroll
                    for (int c = 0; c < 4; ++c)
                        accG[p][c] = __builtin_amdgcn_fdot2(wp, f[c], accG[p][c], false);
                }
            }
        }
        #pragma unroll
        for (int p = 0; p < 4; ++p)
            #pragma unroll
            for (int c = 0; c < 4; ++c)
                gh[p] = fmaf(accS[p][4 * hlf + c], accG[p][c], gh[p]);
    }

    // ---- epilogue: exact fp32 pass-through reloaded from global (L1 hits) ----
    float* outp = out + (size_t)b * (HH * WW);
    #pragma unroll
    for (int p = 0; p < 4; ++p) {
        float cen = img[(size_t)(y0 + p) * WW + x0 + (p & 1)];
        float g = gh[p] * __builtin_amdgcn_rcpf(sum[p]);
        float2 o;
        if ((p & 1) == 0) { o.x = cen; o.y = g; }    // green at x0
        else              { o.x = g;   o.y = cen; }  // green at x0+1
        *(float2*)(outp + (size_t)(y0 + p) * WW + x0) = o;
    }
}

extern "C" void kernel_launch(void* const* d_in, const int* in_sizes, int n_in,
                              void* d_out, int out_size, void* d_ws, size_t ws_size,
                              hipStream_t stream) {
    const float* mosaick     = (const float*)d_in[0];
    const float* sel_filts   = (const float*)d_in[1];
    const float* green_filts = (const float*)d_in[2];
    float* out = (float*)d_out;
    const int HW = HH * WW;
    const int B = in_sizes[0] / HW;          // 8
    dim3 grid(WW / 128, HH / 16, B);         // (8, 64, 8) = 4096 blocks
    dim3 block(64, 4, 1);
    hipLaunchKernelGGL(demosaick_kernel, grid, block, 0, stream,
                       mosaick, sel_filts, green_filts, out);
}